// Round 2
// baseline (1403.714 us; speedup 1.0000x reference)
//
#include <hip/hip_runtime.h>

#define EMBD 384
#define FFN_DIM 1536
#define T_SEQ 200
#define NHEAD 6
#define BATCH 256

typedef __bf16 bf16x8_t __attribute__((ext_vector_type(8)));
typedef short s16x8_t __attribute__((ext_vector_type(8)));
typedef float f32x4_t __attribute__((ext_vector_type(4)));

__device__ __forceinline__ float bf2f(unsigned short h) {
  return __builtin_bit_cast(float, (unsigned)h << 16);
}
__device__ __forceinline__ unsigned short f2bf(float f) {
  unsigned u = __builtin_bit_cast(unsigned, f);
  u += 0x7fffu + ((u >> 16) & 1u);  // RTNE
  return (unsigned short)(u >> 16);
}

// ---------------- dtype detect (hedge: inputs are almost surely bf16) --------
__global__ void detect_dtype(const unsigned short* __restrict__ xr, int* __restrict__ flag) {
  int tid = threadIdx.x;
  int cnt = 0;
  for (int i = tid; i < 4096; i += 256) {
    float a = fabsf(bf2f(xr[2 * i]));
    cnt += (a > 1e-5f && a < 32.f) ? 1 : 0;
  }
#pragma unroll
  for (int off = 32; off; off >>= 1) cnt += __shfl_xor(cnt, off);
  __shared__ int tot;
  if (tid == 0) tot = 0;
  __syncthreads();
  if ((tid & 63) == 0) atomicAdd(&tot, cnt);
  __syncthreads();
  if (tid == 0) *flag = (tot > 2048) ? 1 : 0;
}

__global__ void cvt_vec(const void* __restrict__ src, float* __restrict__ dst, int n,
                        const int* __restrict__ flagp) {
  int i = blockIdx.x * 256 + threadIdx.x;
  if (i >= n) return;
  dst[i] = (*flagp) ? bf2f(((const unsigned short*)src)[i]) : ((const float*)src)[i];
}

// W[K][N] row-major -> Wt[N][K] bf16
__global__ void pack_w(const void* __restrict__ W, unsigned short* __restrict__ Wt,
                       int K, int N, int ldt, const int* __restrict__ flagp) {
  int idx = blockIdx.x * 256 + threadIdx.x;
  if (idx >= K * N) return;
  int k = idx / N, n = idx % N;
  unsigned short v = (*flagp) ? ((const unsigned short*)W)[idx]
                              : f2bf(((const float*)W)[idx]);
  Wt[(size_t)n * ldt + k] = v;
}

// ---------------- LayerNorm: one wave per row of 384 ----------------
__global__ __launch_bounds__(256) void ln_kernel(const void* __restrict__ xin, int row0,
                                                 const float* __restrict__ g,
                                                 const float* __restrict__ be,
                                                 unsigned short* __restrict__ out,
                                                 const int* __restrict__ flagp) {
  int rloc = blockIdx.x * 4 + (threadIdx.x >> 6);
  int lane = threadIdx.x & 63;
  int isbf = flagp ? *flagp : 0;
  size_t row = (size_t)(row0 + rloc);
  float v[6];
  float sum = 0.f;
  if (isbf) {
    const unsigned short* xr = (const unsigned short*)xin + row * EMBD;
#pragma unroll
    for (int i = 0; i < 6; ++i) { v[i] = bf2f(xr[lane + 64 * i]); sum += v[i]; }
  } else {
    const float* xr = (const float*)xin + row * EMBD;
#pragma unroll
    for (int i = 0; i < 6; ++i) { v[i] = xr[lane + 64 * i]; sum += v[i]; }
  }
#pragma unroll
  for (int off = 32; off; off >>= 1) sum += __shfl_xor(sum, off);
  float mean = sum * (1.f / EMBD);
  float var = 0.f;
#pragma unroll
  for (int i = 0; i < 6; ++i) { float d = v[i] - mean; var += d * d; }
#pragma unroll
  for (int off = 32; off; off >>= 1) var += __shfl_xor(var, off);
  float rstd = rsqrtf(var * (1.f / EMBD) + 1e-5f);
  unsigned short* orow = out + (size_t)rloc * EMBD;
#pragma unroll
  for (int i = 0; i < 6; ++i) {
    int c = lane + 64 * i;
    orow[c] = f2bf((v[i] - mean) * rstd * g[c] + be[c]);
  }
}

// ---------------- bf16 MFMA GEMM, 128x64 tile, BK=128 LDS staging ----------------
// C[M][N] = A[M][K] @ Bt[N][K]^T.
// MODE 0: store bf16. MODE 1: bias+relu, bf16.
// MODE 2: +bias +R (R dtype per flag, row-offset rrow0), store fp32.
// MODE 3: +bias +R (fp32), store (bf16 if flag else fp32) at row-offset crow0.
template <int MODE>
__global__ __launch_bounds__(256) void gemm_kernel(
    const unsigned short* __restrict__ A, int lda,
    const unsigned short* __restrict__ Bt, int K,
    const float* __restrict__ bias,
    const void* __restrict__ R, int ldr, int rrow0,
    void* __restrict__ Cv, int ldc, int crow0,
    int Mrows, const int* __restrict__ flagp) {
  __shared__ unsigned short As[128 * 136];  // +8 pad: 272B rows, 16B aligned
  __shared__ unsigned short Bs[64 * 136];
  const int n0 = blockIdx.x * 64;
  const int m0 = blockIdx.y * 128;
  const int tid = threadIdx.x;
  const int seg = tid & 15, r0 = tid >> 4;
  const int wv = tid >> 6, lane = tid & 63;
  const int l = lane & 15, quad = lane >> 4;
  f32x4_t acc[2][4];
#pragma unroll
  for (int i = 0; i < 2; ++i)
#pragma unroll
    for (int j = 0; j < 4; ++j) acc[i][j] = (f32x4_t){0.f, 0.f, 0.f, 0.f};

  for (int kc = 0; kc < K; kc += 128) {
#pragma unroll
    for (int p = 0; p < 8; ++p) {
      int row = r0 + p * 16;
      int ar = m0 + row;              // clamp: stores are guarded anyway
      if (ar >= Mrows) ar = Mrows - 1;
      *(s16x8_t*)&As[row * 136 + seg * 8] =
          *(const s16x8_t*)&A[(size_t)ar * lda + kc + seg * 8];
    }
#pragma unroll
    for (int p = 0; p < 4; ++p) {
      int row = r0 + p * 16;
      *(s16x8_t*)&Bs[row * 136 + seg * 8] =
          *(const s16x8_t*)&Bt[(size_t)(n0 + row) * K + kc + seg * 8];
    }
    __syncthreads();
#pragma unroll
    for (int ks = 0; ks < 4; ++ks) {
      bf16x8_t a0 = *(const bf16x8_t*)&As[(wv * 32 + l) * 136 + ks * 32 + quad * 8];
      bf16x8_t a1 = *(const bf16x8_t*)&As[(wv * 32 + 16 + l) * 136 + ks * 32 + quad * 8];
#pragma unroll
      for (int nt = 0; nt < 4; ++nt) {
        bf16x8_t bfr = *(const bf16x8_t*)&Bs[(nt * 16 + l) * 136 + ks * 32 + quad * 8];
        acc[0][nt] = __builtin_amdgcn_mfma_f32_16x16x32_bf16(a0, bfr, acc[0][nt], 0, 0, 0);
        acc[1][nt] = __builtin_amdgcn_mfma_f32_16x16x32_bf16(a1, bfr, acc[1][nt], 0, 0, 0);
      }
    }
    __syncthreads();
  }

  int isbf = flagp ? *flagp : 0;
#pragma unroll
  for (int mt = 0; mt < 2; ++mt) {
#pragma unroll
    for (int nt = 0; nt < 4; ++nt) {
#pragma unroll
      for (int r = 0; r < 4; ++r) {
        int row = m0 + wv * 32 + mt * 16 + quad * 4 + r;  // C/D: row=quad*4+reg
        int col = n0 + nt * 16 + l;                       //      col=lane&15
        if (row >= Mrows) continue;
        float v = acc[mt][nt][r];
        if (MODE == 0) {
          ((unsigned short*)Cv)[(size_t)row * ldc + col] = f2bf(v);
        } else if (MODE == 1) {
          v += bias[col];
          ((unsigned short*)Cv)[(size_t)row * ldc + col] = f2bf(fmaxf(v, 0.f));
        } else if (MODE == 2) {
          size_t ridx = (size_t)(rrow0 + row) * ldr + col;
          float rv = isbf ? bf2f(((const unsigned short*)R)[ridx]) : ((const float*)R)[ridx];
          ((float*)Cv)[(size_t)row * ldc + col] = v + bias[col] + rv;
        } else {
          float rv = ((const float*)R)[(size_t)row * ldr + col];
          float o = v + bias[col] + rv;
          size_t cidx = (size_t)(crow0 + row) * ldc + col;
          if (isbf)
            ((unsigned short*)Cv)[cidx] = f2bf(o);
          else
            ((float*)Cv)[cidx] = o;
        }
      }
    }
  }
}

// ---------------- attention: one block per (b_local, h) ----------------
__global__ __launch_bounds__(256) void attn_kernel(const unsigned short* __restrict__ qkv,
                                                   unsigned short* __restrict__ att) {
  __shared__ unsigned short Ks[T_SEQ * 72];  // [s][d], stride 72 (144B, 16B aligned)
  __shared__ unsigned short Vt[64 * 208];    // [d][s], stride 208 (416B)
  __shared__ float p_buf[4][256];
  __shared__ float q_s[4][64];
  const int bh = blockIdx.x;
  const int b = bh / NHEAD, h = bh % NHEAD;
  const size_t base = (size_t)b * T_SEQ * 1152;
  const int tid = threadIdx.x;
  for (int idx = tid; idx < T_SEQ * 64; idx += 256) {
    int s = idx >> 6, d = idx & 63;
    const unsigned short* rowp = qkv + base + (size_t)s * 1152 + h * 64;
    Ks[s * 72 + d] = rowp[384 + d];
    Vt[d * 208 + s] = rowp[768 + d];
  }
  __syncthreads();
  const int w = tid >> 6, lane = tid & 63;
  const float scale = 0.051031036307982884f;  // 384^-0.5 (embd, not head_size!)
  for (int t0 = 0; t0 < T_SEQ; t0 += 4) {     // 200 % 4 == 0: syncs stay uniform
    const int t = t0 + w;
    q_s[w][lane] = bf2f(qkv[base + (size_t)t * 1152 + h * 64 + lane]);
    __syncthreads();
    float sreg[4];
    float mloc = -1e30f;
#pragma unroll
    for (int r = 0; r < 4; ++r) {
      sreg[r] = -1e30f;
      int j = r * 64 + lane;
      if (j <= t) {
        float s = 0.f;
        const unsigned short* kr = &Ks[j * 72];
        const float* qr = q_s[w];
#pragma unroll
        for (int d0 = 0; d0 < 64; d0 += 8) {
          s16x8_t kv = *(const s16x8_t*)&kr[d0];
#pragma unroll
          for (int i = 0; i < 8; ++i) s += bf2f((unsigned short)kv[i]) * qr[d0 + i];
        }
        sreg[r] = s * scale;
        mloc = fmaxf(mloc, sreg[r]);
      }
    }
#pragma unroll
    for (int off = 32; off; off >>= 1) mloc = fmaxf(mloc, __shfl_xor(mloc, off));
    float sloc = 0.f;
#pragma unroll
    for (int r = 0; r < 4; ++r) {
      int j = r * 64 + lane;
      if (j <= t) {
        float e = __expf(sreg[r] - mloc);
        p_buf[w][j] = e;
        sloc += e;
      }
    }
#pragma unroll
    for (int off = 32; off; off >>= 1) sloc += __shfl_xor(sloc, off);
    __syncthreads();
    float acc = 0.f;
    const unsigned short* vr = &Vt[lane * 208];
    const float* pr = p_buf[w];
    const int jmax = t + 1;
    int j = 0;
    for (; j + 8 <= jmax; j += 8) {
      s16x8_t vv = *(const s16x8_t*)&vr[j];
#pragma unroll
      for (int i = 0; i < 8; ++i) acc += pr[j + i] * bf2f((unsigned short)vv[i]);
    }
    for (; j < jmax; ++j) acc += pr[j] * bf2f(vr[j]);
    att[((size_t)b * T_SEQ + t) * EMBD + h * 64 + lane] = f2bf(acc / sloc);
  }
}

// ---------------- static workspace layout (weights etc., ~3.6 MB) ----------------
static constexpr size_t OFF_WQKV  = 0;
static constexpr size_t OFF_WPROJ = OFF_WQKV  + (size_t)1152 * 384 * 2;   // 884736
static constexpr size_t OFF_W1    = OFF_WPROJ + (size_t)384 * 384 * 2;    // +294912
static constexpr size_t OFF_W2    = OFF_W1    + (size_t)1536 * 384 * 2;   // +1179648
static constexpr size_t OFF_BIAS  = OFF_W2    + (size_t)384 * 1536 * 2;   // +1179648
static constexpr size_t OFF_FLAG  = OFF_BIAS  + 4096 * 4;
static constexpr size_t OFF_DYN   = OFF_FLAG + 256;  // 3,555,584 (256B aligned)

extern "C" void kernel_launch(void* const* d_in, const int* in_sizes, int n_in,
                              void* d_out, int out_size, void* d_ws, size_t ws_size,
                              hipStream_t stream) {
  const void* x     = d_in[0];
  const void* Wq    = d_in[1];
  const void* Wk    = d_in[2];
  const void* Wv    = d_in[3];
  const void* Wproj = d_in[4];
  const void* bproj = d_in[5];
  const void* W1    = d_in[6];
  const void* b1    = d_in[7];
  const void* W2    = d_in[8];
  const void* b2    = d_in[9];
  const void* g1    = d_in[10];
  const void* be1   = d_in[11];
  const void* g2    = d_in[12];
  const void* be2   = d_in[13];

  char* ws = (char*)d_ws;
  unsigned short* wqkv_t  = (unsigned short*)(ws + OFF_WQKV);
  unsigned short* wproj_t = (unsigned short*)(ws + OFF_WPROJ);
  unsigned short* w1_t    = (unsigned short*)(ws + OFF_W1);
  unsigned short* w2_t    = (unsigned short*)(ws + OFF_W2);
  float*          bias_f  = (float*)(ws + OFF_BIAS);
  int*            flag    = (int*)(ws + OFF_FLAG);

  // Adaptive batch-chunking: footprint = OFF_DYN + Bc*200*6144 bytes.
  // ws_size is constant across calls -> deterministic (graph-safe).
  int Bc = BATCH;
  while (Bc > 1 && OFF_DYN + (size_t)Bc * T_SEQ * 6144 > ws_size) Bc >>= 1;
  if (OFF_DYN + (size_t)Bc * T_SEQ * 6144 > ws_size) return;  // < ~5 MB: hopeless
  const int NC = BATCH / Bc;
  const int Mc = Bc * T_SEQ;
  const int mtiles = (Mc + 127) / 128;

  // Per-chunk dynamic region with lifetime overlays:
  //   bufA [Mc*2304 B]: qkv (steps 2-3); then x2 fp32 [0,Mc*1536) + h2 bf16 [Mc*1536,Mc*2304)
  //   bufB [Mc*768  B]: h (steps 1-2); att (steps 3-4)
  //   bufC [Mc*3072 B]: mid (steps 6-7)
  char* bufA = ws + OFF_DYN;
  char* bufB = bufA + (size_t)Mc * 2304;
  char* bufC = bufB + (size_t)Mc * 768;
  unsigned short* qkv = (unsigned short*)bufA;
  float*          x2  = (float*)bufA;
  unsigned short* h2  = (unsigned short*)(bufA + (size_t)Mc * 1536);
  unsigned short* hb  = (unsigned short*)bufB;  // h, then att
  unsigned short* mid = (unsigned short*)bufC;

  // ---- one-time setup (per call) ----
  detect_dtype<<<1, 256, 0, stream>>>((const unsigned short*)x, flag);
  cvt_vec<<<2, 256, 0, stream>>>(bproj, bias_f + 0,    384,  flag);
  cvt_vec<<<6, 256, 0, stream>>>(b1,    bias_f + 384,  1536, flag);
  cvt_vec<<<2, 256, 0, stream>>>(b2,    bias_f + 1920, 384,  flag);
  cvt_vec<<<2, 256, 0, stream>>>(g1,    bias_f + 2304, 384,  flag);
  cvt_vec<<<2, 256, 0, stream>>>(be1,   bias_f + 2688, 384,  flag);
  cvt_vec<<<2, 256, 0, stream>>>(g2,    bias_f + 3072, 384,  flag);
  cvt_vec<<<2, 256, 0, stream>>>(be2,   bias_f + 3456, 384,  flag);
  pack_w<<<576, 256, 0, stream>>>(Wq,    wqkv_t,                 384,  384,  384,  flag);
  pack_w<<<576, 256, 0, stream>>>(Wk,    wqkv_t + 384 * 384,     384,  384,  384,  flag);
  pack_w<<<576, 256, 0, stream>>>(Wv,    wqkv_t + 2 * 384 * 384, 384,  384,  384,  flag);
  pack_w<<<576, 256, 0, stream>>>(Wproj, wproj_t,                384,  384,  384,  flag);
  pack_w<<<2304, 256, 0, stream>>>(W1,   w1_t,                   384,  1536, 384,  flag);
  pack_w<<<2304, 256, 0, stream>>>(W2,   w2_t,                   1536, 384,  1536, flag);

  for (int c = 0; c < NC; ++c) {
    const int row0 = c * Bc * T_SEQ;
    // 1. h = LN1(x[chunk])
    ln_kernel<<<Mc / 4, 256, 0, stream>>>(x, row0, bias_f + 2304, bias_f + 2688, hb, flag);
    // 2. qkv = h @ [Wq|Wk|Wv]
    gemm_kernel<0><<<dim3(18, mtiles), 256, 0, stream>>>(
        hb, 384, wqkv_t, 384, nullptr, nullptr, 0, 0, qkv, 1152, 0, Mc, nullptr);
    // 3. att = softmax(causal(q k^T * 384^-0.5)) v   (att overlays h)
    attn_kernel<<<Bc * NHEAD, 256, 0, stream>>>(qkv, hb);
    // 4. x2 = x[chunk] + att @ Wproj + bproj   (fp32, overlays dead qkv)
    gemm_kernel<2><<<dim3(6, mtiles), 256, 0, stream>>>(
        hb, 384, wproj_t, 384, bias_f + 0, x, 384, row0, x2, 384, 0, Mc, flag);
    // 5. h2 = LN2(x2)
    ln_kernel<<<Mc / 4, 256, 0, stream>>>(x2, 0, bias_f + 3072, bias_f + 3456, h2, nullptr);
    // 6. mid = relu(h2 @ W1 + b1)
    gemm_kernel<1><<<dim3(24, mtiles), 256, 0, stream>>>(
        h2, 384, w1_t, 384, bias_f + 384, nullptr, 0, 0, mid, 1536, 0, Mc, nullptr);
    // 7. out[chunk] = x2 + mid @ W2 + b2
    gemm_kernel<3><<<dim3(6, mtiles), 256, 0, stream>>>(
        mid, 1536, w2_t, 1536, bias_f + 1920, x2, 384, 0, d_out, 384, row0, Mc, flag);
  }
}

// Round 3
// 781.201 us; speedup vs baseline: 1.7969x; 1.7969x over previous
//
#include <hip/hip_runtime.h>

#define EMBD 384
#define FFN_DIM 1536
#define T_SEQ 200
#define NHEAD 6
#define BATCH 256

typedef __bf16 bf16x8_t __attribute__((ext_vector_type(8)));
typedef short s16x8_t __attribute__((ext_vector_type(8)));
typedef float f32x4_t __attribute__((ext_vector_type(4)));

__device__ __forceinline__ float bf2f(unsigned short h) {
  return __builtin_bit_cast(float, (unsigned)h << 16);
}
__device__ __forceinline__ unsigned short f2bf(float f) {
  unsigned u = __builtin_bit_cast(unsigned, f);
  u += 0x7fffu + ((u >> 16) & 1u);  // RTNE
  return (unsigned short)(u >> 16);
}
// async 16B global->LDS (wave-uniform LDS base + lane*16 implicit)
__device__ __forceinline__ void async_cp16(const void* g, void* l) {
  __builtin_amdgcn_global_load_lds(
      (const __attribute__((address_space(1))) unsigned int*)g,
      (__attribute__((address_space(3))) unsigned int*)l, 16, 0, 0);
}

// ---------------- dtype detect ----------------
__global__ void detect_dtype(const unsigned short* __restrict__ xr, int* __restrict__ flag) {
  int tid = threadIdx.x;
  int cnt = 0;
  for (int i = tid; i < 4096; i += 256) {
    float a = fabsf(bf2f(xr[2 * i]));
    cnt += (a > 1e-5f && a < 32.f) ? 1 : 0;
  }
#pragma unroll
  for (int off = 32; off; off >>= 1) cnt += __shfl_xor(cnt, off);
  __shared__ int tot;
  if (tid == 0) tot = 0;
  __syncthreads();
  if ((tid & 63) == 0) atomicAdd(&tot, cnt);
  __syncthreads();
  if (tid == 0) *flag = (tot > 2048) ? 1 : 0;
}

__global__ void cvt_vec(const void* __restrict__ src, float* __restrict__ dst, int n,
                        const int* __restrict__ flagp) {
  int i = blockIdx.x * 256 + threadIdx.x;
  if (i >= n) return;
  dst[i] = (*flagp) ? bf2f(((const unsigned short*)src)[i]) : ((const float*)src)[i];
}

// W[K][N] row-major -> Wt[N][K] bf16
__global__ void pack_w(const void* __restrict__ W, unsigned short* __restrict__ Wt,
                       int K, int N, int ldt, const int* __restrict__ flagp) {
  int idx = blockIdx.x * 256 + threadIdx.x;
  if (idx >= K * N) return;
  int k = idx / N, n = idx % N;
  unsigned short v = (*flagp) ? ((const unsigned short*)W)[idx]
                              : f2bf(((const float*)W)[idx]);
  Wt[(size_t)n * ldt + k] = v;
}

// ---------------- LayerNorm: one wave per row of 384 ----------------
__global__ __launch_bounds__(256) void ln_kernel(const void* __restrict__ xin, int row0,
                                                 const float* __restrict__ g,
                                                 const float* __restrict__ be,
                                                 unsigned short* __restrict__ out,
                                                 const int* __restrict__ flagp) {
  int rloc = blockIdx.x * 4 + (threadIdx.x >> 6);
  int lane = threadIdx.x & 63;
  int isbf = flagp ? *flagp : 0;
  size_t row = (size_t)(row0 + rloc);
  float v[6];
  float sum = 0.f;
  if (isbf) {
    const unsigned short* xr = (const unsigned short*)xin + row * EMBD;
#pragma unroll
    for (int i = 0; i < 6; ++i) { v[i] = bf2f(xr[lane + 64 * i]); sum += v[i]; }
  } else {
    const float* xr = (const float*)xin + row * EMBD;
#pragma unroll
    for (int i = 0; i < 6; ++i) { v[i] = xr[lane + 64 * i]; sum += v[i]; }
  }
#pragma unroll
  for (int off = 32; off; off >>= 1) sum += __shfl_xor(sum, off);
  float mean = sum * (1.f / EMBD);
  float var = 0.f;
#pragma unroll
  for (int i = 0; i < 6; ++i) { float d = v[i] - mean; var += d * d; }
#pragma unroll
  for (int off = 32; off; off >>= 1) var += __shfl_xor(var, off);
  float rstd = rsqrtf(var * (1.f / EMBD) + 1e-5f);
  unsigned short* orow = out + (size_t)rloc * EMBD;
#pragma unroll
  for (int i = 0; i < 6; ++i) {
    int c = lane + 64 * i;
    orow[c] = f2bf((v[i] - mean) * rstd * g[c] + be[c]);
  }
}

// ------------- bf16 MFMA GEMM: 128x128 block, 64x64 wave tile, BK=64 -------------
// C[M][N] = A[M][K] @ Bt[N][K]^T.  LDS XOR-swizzled (16B chunk: row*8 + (kc^(row&7)))
// staged via global_load_lds width=16.  MODE 0: bf16. MODE 1: bias+relu bf16.
// MODE 2: +bias +R(flag dtype)@rrow0 -> fp32. MODE 3: +bias +R(fp32) -> bf16/fp32 @crow0.
template <int MODE>
__global__ __launch_bounds__(256, 3) void gemm_kernel(
    const unsigned short* __restrict__ A, int lda,
    const unsigned short* __restrict__ Bt, int K,
    const float* __restrict__ bias,
    const void* __restrict__ R, int ldr, int rrow0,
    void* __restrict__ Cv, int ldc, int crow0,
    int Mrows, const int* __restrict__ flagp) {
  __shared__ unsigned short As[128 * 64];  // 16 KB, swizzled
  __shared__ unsigned short Bs[128 * 64];  // 16 KB, swizzled
  const int n0 = blockIdx.x * 128;
  const int m0 = blockIdx.y * 128;
  const int tid = threadIdx.x;
  const int wv = tid >> 6, lane = tid & 63;
  const int wr = wv >> 1, wc = wv & 1;
  const int l = lane & 15, quad = lane >> 4;
  f32x4_t acc[4][4];
#pragma unroll
  for (int i = 0; i < 4; ++i)
#pragma unroll
    for (int j = 0; j < 4; ++j) acc[i][j] = (f32x4_t){0.f, 0.f, 0.f, 0.f};

  for (int kc = 0; kc < K; kc += 64) {
#pragma unroll
    for (int i = 0; i < 4; ++i) {  // A: 1024 chunks, this wave's 4x64
      int c = (wv * 4 + i) * 64 + lane;
      int row = c >> 3;
      int kk = ((c & 7) ^ (row & 7)) * 8;
      int ar = m0 + row;
      if (ar >= Mrows) ar = Mrows - 1;
      async_cp16(A + (size_t)ar * lda + kc + kk, As + (wv * 4 + i) * 512);
    }
#pragma unroll
    for (int i = 0; i < 4; ++i) {  // B
      int c = (wv * 4 + i) * 64 + lane;
      int row = c >> 3;
      int kk = ((c & 7) ^ (row & 7)) * 8;
      async_cp16(Bt + (size_t)(n0 + row) * K + kc + kk, Bs + (wv * 4 + i) * 512);
    }
    __syncthreads();
#pragma unroll
    for (int ks = 0; ks < 2; ++ks) {
      bf16x8_t af[4], bfr[4];
#pragma unroll
      for (int g = 0; g < 4; ++g) {
        int row = wr * 64 + g * 16 + l;
        int ch = row * 8 + ((quad + ks * 4) ^ (row & 7));
        af[g] = *(const bf16x8_t*)&As[ch * 8];
        int nrw = wc * 64 + g * 16 + l;
        int nch = nrw * 8 + ((quad + ks * 4) ^ (nrw & 7));
        bfr[g] = *(const bf16x8_t*)&Bs[nch * 8];
      }
#pragma unroll
      for (int i = 0; i < 4; ++i)
#pragma unroll
        for (int j = 0; j < 4; ++j)
          acc[i][j] = __builtin_amdgcn_mfma_f32_16x16x32_bf16(af[i], bfr[j], acc[i][j], 0, 0, 0);
    }
    __syncthreads();
  }

  int isbf = flagp ? *flagp : 0;
#pragma unroll
  for (int i = 0; i < 4; ++i) {
#pragma unroll
    for (int j = 0; j < 4; ++j) {
#pragma unroll
      for (int r = 0; r < 4; ++r) {
        int row = m0 + wr * 64 + i * 16 + quad * 4 + r;  // C/D: row=quad*4+reg
        int col = n0 + wc * 64 + j * 16 + l;             //      col=lane&15
        if (row >= Mrows) continue;
        float v = acc[i][j][r];
        if (MODE == 0) {
          ((unsigned short*)Cv)[(size_t)row * ldc + col] = f2bf(v);
        } else if (MODE == 1) {
          v += bias[col];
          ((unsigned short*)Cv)[(size_t)row * ldc + col] = f2bf(fmaxf(v, 0.f));
        } else if (MODE == 2) {
          size_t ridx = (size_t)(rrow0 + row) * ldr + col;
          float rv = isbf ? bf2f(((const unsigned short*)R)[ridx]) : ((const float*)R)[ridx];
          ((float*)Cv)[(size_t)row * ldc + col] = v + bias[col] + rv;
        } else {
          float rv = ((const float*)R)[(size_t)row * ldr + col];
          float o = v + bias[col] + rv;
          size_t cidx = (size_t)(crow0 + row) * ldc + col;
          if (isbf)
            ((unsigned short*)Cv)[cidx] = f2bf(o);
          else
            ((float*)Cv)[cidx] = o;
        }
      }
    }
  }
}

// ---------------- MFMA attention: one block per (b_local, h) ----------------
// S = Q K^T (16x16x32 mfma, causal tile-skip), softmax in C-layout regs,
// P -> wave-private LDS rows (bf16), O = P V^T-layout mfma. No barriers in loop.
__global__ __launch_bounds__(256, 1) void attn_kernel(const unsigned short* __restrict__ qkv,
                                                      unsigned short* __restrict__ att) {
  __shared__ unsigned short Ks[208 * 64];  // swizzled chunks, 26.6 KB
  __shared__ unsigned short Vt[64 * 232];  // [d][s], stride 232 (2-way free), 29.7 KB
  __shared__ unsigned short Ps[64 * 232];  // P rows (wave-private 16-row bands), 29.7 KB
  const int bh = blockIdx.x;
  const int b = bh / NHEAD, h = bh % NHEAD;
  const size_t base = (size_t)b * T_SEQ * 1152;
  const int tid = threadIdx.x;
  const int w = tid >> 6, lane = tid & 63;
  const int l = lane & 15, quad = lane >> 4;

  // K: 208 rows x 64 d, swizzled async staging (rows >=200 read stale ws: masked later)
  for (int i = w; i < 26; i += 4) {
    int c = i * 64 + lane;
    int s = c >> 3;
    int kk = ((c & 7) ^ (s & 7)) * 8;
    async_cp16(qkv + base + (size_t)s * 1152 + 384 + h * 64 + kk, Ks + i * 512);
  }
  // V transposed: Vt[d][s]
  for (int idx = tid; idx < 1600; idx += 256) {
    int s = idx >> 3, d0 = (idx & 7) * 8;
    s16x8_t vv = *(const s16x8_t*)(qkv + base + (size_t)s * 1152 + 768 + h * 64 + d0);
#pragma unroll
    for (int i = 0; i < 8; ++i) Vt[(d0 + i) * 232 + s] = (unsigned short)vv[i];
  }
  for (int idx = tid; idx < 64 * 32; idx += 256) {  // zero pad cols 200..231
    int d = idx >> 5, c = idx & 31;
    Vt[d * 232 + 200 + c] = 0;
  }
  __syncthreads();

  const float scale = 0.051031036307982884f;  // 384^-0.5 (embd, not head_size!)
  for (int t0 = 0; t0 < T_SEQ; t0 += 64) {
    if (t0 + w * 16 >= T_SEQ) continue;  // wave-level skip, no barriers inside
    // Q A-frags from global (rows t0+w*16+l, k=quad*8(+32))
    int tq = t0 + w * 16 + l;
    const unsigned short* qp = qkv + base + (size_t)tq * 1152 + h * 64;
    bf16x8_t qa0 = *(const bf16x8_t*)(qp + quad * 8);
    bf16x8_t qa1 = *(const bf16x8_t*)(qp + 32 + quad * 8);
    const int cmax = (t0 >> 4) + w + 1;  // causal col-tile count
    f32x4_t sa[13];
#pragma unroll
    for (int c = 0; c < 13; ++c) {
      if (c < cmax) {
        int s = c * 16 + l;
        int ch0 = s * 8 + (quad ^ (s & 7));
        int ch1 = s * 8 + ((quad + 4) ^ (s & 7));
        bf16x8_t kb0 = *(const bf16x8_t*)&Ks[ch0 * 8];
        bf16x8_t kb1 = *(const bf16x8_t*)&Ks[ch1 * 8];
        f32x4_t z = (f32x4_t){0.f, 0.f, 0.f, 0.f};
        z = __builtin_amdgcn_mfma_f32_16x16x32_bf16(qa0, kb0, z, 0, 0, 0);
        sa[c] = __builtin_amdgcn_mfma_f32_16x16x32_bf16(qa1, kb1, z, 0, 0, 0);
      }
    }
    // zero my 16 Ps rows (stale cols from previous tile)
    {
      s16x8_t zz = {0, 0, 0, 0, 0, 0, 0, 0};
#pragma unroll
      for (int i = 0; i < 8; ++i) {
        int c = i * 64 + lane;
        if (c < 464) *(s16x8_t*)&Ps[w * 16 * 232 + c * 8] = zz;
      }
    }
    // softmax per row (4 rows/lane-group), write normalized P (bf16)
#pragma unroll
    for (int r = 0; r < 4; ++r) {
      int t = t0 + w * 16 + quad * 4 + r;
      float tv[13];
      float mx = -1e30f;
#pragma unroll
      for (int c = 0; c < 13; ++c) {
        if (c < cmax) {
          int col = c * 16 + l;
          float v = sa[c][r] * scale;
          tv[c] = (col <= t) ? v : -1e30f;
          mx = fmaxf(mx, tv[c]);
        }
      }
#pragma unroll
      for (int off = 1; off < 16; off <<= 1) mx = fmaxf(mx, __shfl_xor(mx, off));
      float sum = 0.f;
#pragma unroll
      for (int c = 0; c < 13; ++c) {
        if (c < cmax) {
          float p = __expf(tv[c] - mx);
          tv[c] = p;
          sum += p;
        }
      }
#pragma unroll
      for (int off = 1; off < 16; off <<= 1) sum += __shfl_xor(sum, off);
      float inv = 1.f / sum;
#pragma unroll
      for (int c = 0; c < 13; ++c) {
        if (c < cmax)
          Ps[(w * 16 + quad * 4 + r) * 232 + c * 16 + l] = f2bf(tv[c] * inv);
      }
    }
    // O = P @ V : A from Ps (my rows), B from Vt
    int smax = t0 + w * 16 + 16;
    if (smax > T_SEQ) smax = T_SEQ;
    const int ksteps = (smax + 31) >> 5;
    f32x4_t oa[4];
#pragma unroll
    for (int d = 0; d < 4; ++d) oa[d] = (f32x4_t){0.f, 0.f, 0.f, 0.f};
    for (int ks = 0; ks < ksteps; ++ks) {
      bf16x8_t pa = *(const bf16x8_t*)&Ps[(w * 16 + l) * 232 + ks * 32 + quad * 8];
#pragma unroll
      for (int d = 0; d < 4; ++d) {
        bf16x8_t vb = *(const bf16x8_t*)&Vt[(d * 16 + l) * 232 + ks * 32 + quad * 8];
        oa[d] = __builtin_amdgcn_mfma_f32_16x16x32_bf16(pa, vb, oa[d], 0, 0, 0);
      }
    }
#pragma unroll
    for (int d = 0; d < 4; ++d) {
#pragma unroll
      for (int r = 0; r < 4; ++r) {
        int t = t0 + w * 16 + quad * 4 + r;
        if (t < T_SEQ)
          att[((size_t)b * T_SEQ + t) * EMBD + h * 64 + d * 16 + l] = f2bf(oa[d][r]);
      }
    }
  }
}

// ---------------- static workspace layout (~3.6 MB) ----------------
static constexpr size_t OFF_WQKV  = 0;
static constexpr size_t OFF_WPROJ = OFF_WQKV  + (size_t)1152 * 384 * 2;
static constexpr size_t OFF_W1    = OFF_WPROJ + (size_t)384 * 384 * 2;
static constexpr size_t OFF_W2    = OFF_W1    + (size_t)1536 * 384 * 2;
static constexpr size_t OFF_BIAS  = OFF_W2    + (size_t)384 * 1536 * 2;
static constexpr size_t OFF_FLAG  = OFF_BIAS  + 4096 * 4;
static constexpr size_t OFF_DYN   = OFF_FLAG + 256;

extern "C" void kernel_launch(void* const* d_in, const int* in_sizes, int n_in,
                              void* d_out, int out_size, void* d_ws, size_t ws_size,
                              hipStream_t stream) {
  const void* x     = d_in[0];
  const void* Wq    = d_in[1];
  const void* Wk    = d_in[2];
  const void* Wv    = d_in[3];
  const void* Wproj = d_in[4];
  const void* bproj = d_in[5];
  const void* W1    = d_in[6];
  const void* b1    = d_in[7];
  const void* W2    = d_in[8];
  const void* b2    = d_in[9];
  const void* g1    = d_in[10];
  const void* be1   = d_in[11];
  const void* g2    = d_in[12];
  const void* be2   = d_in[13];

  char* ws = (char*)d_ws;
  unsigned short* wqkv_t  = (unsigned short*)(ws + OFF_WQKV);
  unsigned short* wproj_t = (unsigned short*)(ws + OFF_WPROJ);
  unsigned short* w1_t    = (unsigned short*)(ws + OFF_W1);
  unsigned short* w2_t    = (unsigned short*)(ws + OFF_W2);
  float*          bias_f  = (float*)(ws + OFF_BIAS);
  int*            flag    = (int*)(ws + OFF_FLAG);

  // Adaptive batch-chunking: footprint = OFF_DYN + Bc*200*6144 bytes.
  int Bc = BATCH;
  while (Bc > 1 && OFF_DYN + (size_t)Bc * T_SEQ * 6144 > ws_size) Bc >>= 1;
  if (OFF_DYN + (size_t)Bc * T_SEQ * 6144 > ws_size) return;
  const int NC = BATCH / Bc;
  const int Mc = Bc * T_SEQ;
  const int mtiles = (Mc + 127) / 128;

  char* bufA = ws + OFF_DYN;                  // qkv; then x2(fp32)+h2
  char* bufB = bufA + (size_t)Mc * 2304;      // h; then att
  char* bufC = bufB + (size_t)Mc * 768;       // mid
  unsigned short* qkv = (unsigned short*)bufA;
  float*          x2  = (float*)bufA;
  unsigned short* h2  = (unsigned short*)(bufA + (size_t)Mc * 1536);
  unsigned short* hb  = (unsigned short*)bufB;
  unsigned short* mid = (unsigned short*)bufC;

  detect_dtype<<<1, 256, 0, stream>>>((const unsigned short*)x, flag);
  cvt_vec<<<2, 256, 0, stream>>>(bproj, bias_f + 0,    384,  flag);
  cvt_vec<<<6, 256, 0, stream>>>(b1,    bias_f + 384,  1536, flag);
  cvt_vec<<<2, 256, 0, stream>>>(b2,    bias_f + 1920, 384,  flag);
  cvt_vec<<<2, 256, 0, stream>>>(g1,    bias_f + 2304, 384,  flag);
  cvt_vec<<<2, 256, 0, stream>>>(be1,   bias_f + 2688, 384,  flag);
  cvt_vec<<<2, 256, 0, stream>>>(g2,    bias_f + 3072, 384,  flag);
  cvt_vec<<<2, 256, 0, stream>>>(be2,   bias_f + 3456, 384,  flag);
  pack_w<<<576, 256, 0, stream>>>(Wq,    wqkv_t,                 384,  384,  384,  flag);
  pack_w<<<576, 256, 0, stream>>>(Wk,    wqkv_t + 384 * 384,     384,  384,  384,  flag);
  pack_w<<<576, 256, 0, stream>>>(Wv,    wqkv_t + 2 * 384 * 384, 384,  384,  384,  flag);
  pack_w<<<576, 256, 0, stream>>>(Wproj, wproj_t,                384,  384,  384,  flag);
  pack_w<<<2304, 256, 0, stream>>>(W1,   w1_t,                   384,  1536, 384,  flag);
  pack_w<<<2304, 256, 0, stream>>>(W2,   w2_t,                   1536, 384,  1536, flag);

  for (int c = 0; c < NC; ++c) {
    const int row0 = c * Bc * T_SEQ;
    ln_kernel<<<Mc / 4, 256, 0, stream>>>(x, row0, bias_f + 2304, bias_f + 2688, hb, flag);
    gemm_kernel<0><<<dim3(9, mtiles), 256, 0, stream>>>(
        hb, 384, wqkv_t, 384, nullptr, nullptr, 0, 0, qkv, 1152, 0, Mc, nullptr);
    attn_kernel<<<Bc * NHEAD, 256, 0, stream>>>(qkv, hb);
    gemm_kernel<2><<<dim3(3, mtiles), 256, 0, stream>>>(
        hb, 384, wproj_t, 384, bias_f + 0, x, 384, row0, x2, 384, 0, Mc, flag);
    ln_kernel<<<Mc / 4, 256, 0, stream>>>(x2, 0, bias_f + 3072, bias_f + 3456, h2, nullptr);
    gemm_kernel<1><<<dim3(12, mtiles), 256, 0, stream>>>(
        h2, 384, w1_t, 384, bias_f + 384, nullptr, 0, 0, mid, 1536, 0, Mc, nullptr);
    gemm_kernel<3><<<dim3(3, mtiles), 256, 0, stream>>>(
        mid, 1536, w2_t, 1536, bias_f + 1920, x2, 384, 0, d_out, 384, row0, Mc, flag);
  }
}

// Round 4
// 679.338 us; speedup vs baseline: 2.0663x; 1.1499x over previous
//
#include <hip/hip_runtime.h>

#define EMBD 384
#define FFN_DIM 1536
#define T_SEQ 200
#define NHEAD 6
#define BATCH 256

typedef __bf16 bf16x8_t __attribute__((ext_vector_type(8)));
typedef short s16x8_t __attribute__((ext_vector_type(8)));
typedef float f32x4_t __attribute__((ext_vector_type(4)));

__device__ __forceinline__ float bf2f(unsigned short h) {
  return __builtin_bit_cast(float, (unsigned)h << 16);
}
__device__ __forceinline__ unsigned short f2bf(float f) {
  unsigned u = __builtin_bit_cast(unsigned, f);
  u += 0x7fffu + ((u >> 16) & 1u);  // RTNE
  return (unsigned short)(u >> 16);
}
__device__ __forceinline__ void async_cp16(const void* g, void* l) {
  __builtin_amdgcn_global_load_lds(
      (const __attribute__((address_space(1))) unsigned int*)g,
      (__attribute__((address_space(3))) unsigned int*)l, 16, 0, 0);
}

// ---------------- dtype detect ----------------
__global__ void detect_dtype(const unsigned short* __restrict__ xr, int* __restrict__ flag) {
  int tid = threadIdx.x;
  int cnt = 0;
  for (int i = tid; i < 4096; i += 256) {
    float a = fabsf(bf2f(xr[2 * i]));
    cnt += (a > 1e-5f && a < 32.f) ? 1 : 0;
  }
#pragma unroll
  for (int off = 32; off; off >>= 1) cnt += __shfl_xor(cnt, off);
  __shared__ int tot;
  if (tid == 0) tot = 0;
  __syncthreads();
  if ((tid & 63) == 0) atomicAdd(&tot, cnt);
  __syncthreads();
  if (tid == 0) *flag = (tot > 2048) ? 1 : 0;
}

// ---------------- fused bias/gain convert: 7 vectors -> bias_f ----------------
__global__ void cvt_all(const void* bproj, const void* b1, const void* b2,
                        const void* g1, const void* be1, const void* g2, const void* be2,
                        float* __restrict__ dst, const int* __restrict__ flagp) {
  int i = blockIdx.x * 256 + threadIdx.x;
  if (i >= 3840) return;
  const void* src; int loc;
  if (i < 384)       { src = bproj; loc = i; }
  else if (i < 1920) { src = b1;    loc = i - 384; }
  else if (i < 2304) { src = b2;    loc = i - 1920; }
  else if (i < 2688) { src = g1;    loc = i - 2304; }
  else if (i < 3072) { src = be1;   loc = i - 2688; }
  else if (i < 3456) { src = g2;    loc = i - 3072; }
  else               { src = be2;   loc = i - 3456; }
  dst[i] = (*flagp) ? bf2f(((const unsigned short*)src)[loc]) : ((const float*)src)[loc];
}

// ---------------- static workspace layout (~3.6 MB) ----------------
static constexpr size_t OFF_WQKV  = 0;
static constexpr size_t OFF_WPROJ = OFF_WQKV  + (size_t)1152 * 384 * 2;
static constexpr size_t OFF_W1    = OFF_WPROJ + (size_t)384 * 384 * 2;
static constexpr size_t OFF_W2    = OFF_W1    + (size_t)1536 * 384 * 2;
static constexpr size_t OFF_BIAS  = OFF_W2    + (size_t)384 * 1536 * 2;
static constexpr size_t OFF_FLAG  = OFF_BIAS  + 4096 * 4;
static constexpr size_t OFF_DYN   = OFF_FLAG + 256;

// ---------------- fused weight pack: all 6 weights -> Wt[N][K] bf16 ----------------
__global__ void pack_all(const void* Wq, const void* Wk, const void* Wv, const void* Wp,
                         const void* W1, const void* W2, char* __restrict__ ws,
                         const int* __restrict__ flagp) {
  int idx = blockIdx.x * 256 + threadIdx.x;
  if (idx >= 1769472) return;
  const void* W; unsigned short* Wt; int loc, K, N, ldt;
  if (idx < 589824) {
    int which = idx / 147456;
    loc = idx - which * 147456; K = 384; N = 384; ldt = 384;
    if (which == 0)      { W = Wq; Wt = (unsigned short*)(ws + OFF_WQKV); }
    else if (which == 1) { W = Wk; Wt = (unsigned short*)(ws + OFF_WQKV) + 147456; }
    else if (which == 2) { W = Wv; Wt = (unsigned short*)(ws + OFF_WQKV) + 294912; }
    else                 { W = Wp; Wt = (unsigned short*)(ws + OFF_WPROJ); }
  } else if (idx < 1179648) {
    loc = idx - 589824; K = 384; N = 1536; ldt = 384;
    W = W1; Wt = (unsigned short*)(ws + OFF_W1);
  } else {
    loc = idx - 1179648; K = 1536; N = 384; ldt = 1536;
    W = W2; Wt = (unsigned short*)(ws + OFF_W2);
  }
  int k = loc / N, n = loc % N;
  unsigned short v = (*flagp) ? ((const unsigned short*)W)[loc]
                              : f2bf(((const float*)W)[loc]);
  Wt[(size_t)n * ldt + k] = v;
}

// ---------------- LayerNorm: one wave per row, vectorized bf16x8 ----------------
// isbf_mode: -1 = read *flagp, 0 = fp32 input, 1 = bf16 input.
__global__ __launch_bounds__(256) void ln_kernel(const void* __restrict__ xin, int row0,
                                                 const float* __restrict__ g,
                                                 const float* __restrict__ be,
                                                 unsigned short* __restrict__ out,
                                                 int isbf_mode, const int* __restrict__ flagp) {
  int rloc = blockIdx.x * 4 + (threadIdx.x >> 6);
  int lane = threadIdx.x & 63;
  int isbf = (isbf_mode >= 0) ? isbf_mode : *flagp;
  size_t row = (size_t)(row0 + rloc);
  float v[8];
  float sum = 0.f;
  const int act = lane < 48;
  const int c0 = lane * 8;
  if (act) {
    if (isbf) {
      s16x8_t xv = *(const s16x8_t*)((const unsigned short*)xin + row * EMBD + c0);
#pragma unroll
      for (int i = 0; i < 8; ++i) { v[i] = bf2f((unsigned short)xv[i]); sum += v[i]; }
    } else {
      const float* xr = (const float*)xin + row * EMBD + c0;
#pragma unroll
      for (int i = 0; i < 8; ++i) { v[i] = xr[i]; sum += v[i]; }
    }
  } else {
#pragma unroll
    for (int i = 0; i < 8; ++i) v[i] = 0.f;
  }
#pragma unroll
  for (int off = 32; off; off >>= 1) sum += __shfl_xor(sum, off);
  float mean = sum * (1.f / EMBD);
  float var = 0.f;
  if (act) {
#pragma unroll
    for (int i = 0; i < 8; ++i) { float d = v[i] - mean; var += d * d; }
  }
#pragma unroll
  for (int off = 32; off; off >>= 1) var += __shfl_xor(var, off);
  float rstd = rsqrtf(var * (1.f / EMBD) + 1e-5f);
  if (act) {
    s16x8_t ov;
#pragma unroll
    for (int i = 0; i < 8; ++i)
      ov[i] = (short)f2bf((v[i] - mean) * rstd * g[c0 + i] + be[c0 + i]);
    *(s16x8_t*)(out + (size_t)rloc * EMBD + c0) = ov;
  }
}

// ------------- bf16 MFMA GEMM: 128x128 block, 64x64 wave tile, BK=64 -------------
// 1-D grid, XCD-swizzled: all NX n-tiles of an m-group land on one XCD (A-tile
// fetched from HBM once, served from that XCD's L2). LDS XOR-swizzled,
// global_load_lds width=16 staging.
// MODE 0: bf16. MODE 1: bias+relu bf16. MODE 2: +bias +R(flag dtype)@rrow0 -> bf16.
// MODE 3: +bias +R(bf16) -> (bf16 if flag else fp32) @crow0.
template <int MODE>
__global__ __launch_bounds__(256, 3) void gemm_kernel(
    const unsigned short* __restrict__ A, int lda,
    const unsigned short* __restrict__ Bt, int K,
    const float* __restrict__ bias,
    const void* __restrict__ R, int ldr, int rrow0,
    void* __restrict__ Cv, int ldc, int crow0,
    int Mrows, int NX, int NY, const int* __restrict__ flagp) {
  __shared__ unsigned short As[128 * 64];  // 16 KB, swizzled
  __shared__ unsigned short Bs[128 * 64];
  const int g = blockIdx.x;
  const int xcd = g & 7, s = g >> 3;
  const int j = s / NX, xn = s - j * NX;
  const int y = xcd + 8 * j;
  if (y >= NY) return;
  const int n0 = xn * 128;
  const int m0 = y * 128;
  const int tid = threadIdx.x;
  const int wv = tid >> 6, lane = tid & 63;
  const int wr = wv >> 1, wc = wv & 1;
  const int l = lane & 15, quad = lane >> 4;
  f32x4_t acc[4][4];
#pragma unroll
  for (int i = 0; i < 4; ++i)
#pragma unroll
    for (int jj = 0; jj < 4; ++jj) acc[i][jj] = (f32x4_t){0.f, 0.f, 0.f, 0.f};

  for (int kc = 0; kc < K; kc += 64) {
#pragma unroll
    for (int i = 0; i < 4; ++i) {
      int c = (wv * 4 + i) * 64 + lane;
      int row = c >> 3;
      int kk = ((c & 7) ^ (row & 7)) * 8;
      int ar = m0 + row;
      if (ar >= Mrows) ar = Mrows - 1;
      async_cp16(A + (size_t)ar * lda + kc + kk, As + (wv * 4 + i) * 512);
    }
#pragma unroll
    for (int i = 0; i < 4; ++i) {
      int c = (wv * 4 + i) * 64 + lane;
      int row = c >> 3;
      int kk = ((c & 7) ^ (row & 7)) * 8;
      async_cp16(Bt + (size_t)(n0 + row) * K + kc + kk, Bs + (wv * 4 + i) * 512);
    }
    __syncthreads();
#pragma unroll
    for (int ks = 0; ks < 2; ++ks) {
      bf16x8_t af[4], bfr[4];
#pragma unroll
      for (int gg = 0; gg < 4; ++gg) {
        int row = wr * 64 + gg * 16 + l;
        int ch = row * 8 + ((quad + ks * 4) ^ (row & 7));
        af[gg] = *(const bf16x8_t*)&As[ch * 8];
        int nrw = wc * 64 + gg * 16 + l;
        int nch = nrw * 8 + ((quad + ks * 4) ^ (nrw & 7));
        bfr[gg] = *(const bf16x8_t*)&Bs[nch * 8];
      }
#pragma unroll
      for (int i = 0; i < 4; ++i)
#pragma unroll
        for (int jj = 0; jj < 4; ++jj)
          acc[i][jj] = __builtin_amdgcn_mfma_f32_16x16x32_bf16(af[i], bfr[jj], acc[i][jj], 0, 0, 0);
    }
    __syncthreads();
  }

  int isbf = flagp ? *flagp : 1;
#pragma unroll
  for (int i = 0; i < 4; ++i) {
#pragma unroll
    for (int jj = 0; jj < 4; ++jj) {
#pragma unroll
      for (int r = 0; r < 4; ++r) {
        int row = m0 + wr * 64 + i * 16 + quad * 4 + r;  // C/D: row=quad*4+reg
        int col = n0 + wc * 64 + jj * 16 + l;            //      col=lane&15
        if (row >= Mrows) continue;
        float v = acc[i][jj][r];
        if (MODE == 0) {
          ((unsigned short*)Cv)[(size_t)row * ldc + col] = f2bf(v);
        } else if (MODE == 1) {
          v += bias[col];
          ((unsigned short*)Cv)[(size_t)row * ldc + col] = f2bf(fmaxf(v, 0.f));
        } else if (MODE == 2) {
          size_t ridx = (size_t)(rrow0 + row) * ldr + col;
          float rv = isbf ? bf2f(((const unsigned short*)R)[ridx]) : ((const float*)R)[ridx];
          ((unsigned short*)Cv)[(size_t)row * ldc + col] = f2bf(v + bias[col] + rv);
        } else {
          float rv = bf2f(((const unsigned short*)R)[(size_t)row * ldr + col]);
          float o = v + bias[col] + rv;
          size_t cidx = (size_t)(crow0 + row) * ldc + col;
          if (isbf)
            ((unsigned short*)Cv)[cidx] = f2bf(o);
          else
            ((float*)Cv)[cidx] = o;
        }
      }
    }
  }
}

// ---------------- MFMA attention: one block per (b_local, h) ----------------
// K/Q frags direct from global (16 B/lane). LDS: V^T + P only (59 KB -> 2 blocks/CU).
// No barriers in the t0 loop.
__global__ __launch_bounds__(256, 2) void attn_kernel(const unsigned short* __restrict__ qkv,
                                                      unsigned short* __restrict__ att) {
  __shared__ unsigned short Vt[64 * 232];  // [d][s], stride 232 (2-way free)
  __shared__ unsigned short Ps[64 * 232];  // P rows (wave-private 16-row bands)
  const int bh = blockIdx.x;
  const int b = bh / NHEAD, h = bh % NHEAD;
  const size_t base = (size_t)b * T_SEQ * 1152;
  const int tid = threadIdx.x;
  const int w = tid >> 6, lane = tid & 63;
  const int l = lane & 15, quad = lane >> 4;

  // V transposed: Vt[d][s]; zero pad s in [200,232); zero all of Ps once.
  for (int idx = tid; idx < 1600; idx += 256) {
    int s = idx >> 3, d0 = (idx & 7) * 8;
    s16x8_t vv = *(const s16x8_t*)(qkv + base + (size_t)s * 1152 + 768 + h * 64 + d0);
#pragma unroll
    for (int i = 0; i < 8; ++i) Vt[(d0 + i) * 232 + s] = (unsigned short)vv[i];
  }
  for (int idx = tid; idx < 64 * 32; idx += 256) {
    int d = idx >> 5, c = idx & 31;
    Vt[d * 232 + 200 + c] = 0;
  }
  {
    s16x8_t zz = {0, 0, 0, 0, 0, 0, 0, 0};
    for (int idx = tid; idx < 1856; idx += 256) *(s16x8_t*)&Ps[idx * 8] = zz;
  }
  __syncthreads();

  const float scale = 0.051031036307982884f;  // 384^-0.5 (embd, not head_size!)
  const unsigned short* kp = qkv + base + 384 + h * 64;
  for (int t0 = 0; t0 < T_SEQ; t0 += 64) {
    if (t0 + w * 16 >= T_SEQ) continue;  // wave-uniform, no barriers inside
    int tq = t0 + w * 16 + l;
    const unsigned short* qp = qkv + base + (size_t)tq * 1152 + h * 64;
    bf16x8_t qa0 = *(const bf16x8_t*)(qp + quad * 8);
    bf16x8_t qa1 = *(const bf16x8_t*)(qp + 32 + quad * 8);
    const int cmax = (t0 >> 4) + w + 1;  // causal col-tile count
    f32x4_t sa[13];
#pragma unroll
    for (int c = 0; c < 13; ++c) {
      if (c < cmax) {
        const unsigned short* kr = kp + (size_t)(c * 16 + l) * 1152;
        bf16x8_t kb0 = *(const bf16x8_t*)(kr + quad * 8);
        bf16x8_t kb1 = *(const bf16x8_t*)(kr + 32 + quad * 8);
        f32x4_t z = (f32x4_t){0.f, 0.f, 0.f, 0.f};
        z = __builtin_amdgcn_mfma_f32_16x16x32_bf16(qa0, kb0, z, 0, 0, 0);
        sa[c] = __builtin_amdgcn_mfma_f32_16x16x32_bf16(qa1, kb1, z, 0, 0, 0);
      }
    }
    // softmax per row (C-layout: rows quad*4+r, cols l across 16 lanes)
#pragma unroll
    for (int r = 0; r < 4; ++r) {
      int t = t0 + w * 16 + quad * 4 + r;
      float tv[13];
      float mx = -1e30f;
#pragma unroll
      for (int c = 0; c < 13; ++c) {
        if (c < cmax) {
          int col = c * 16 + l;
          float v = sa[c][r] * scale;
          tv[c] = (col <= t) ? v : -1e30f;
          mx = fmaxf(mx, tv[c]);
        }
      }
#pragma unroll
      for (int off = 1; off < 16; off <<= 1) mx = fmaxf(mx, __shfl_xor(mx, off));
      float sum = 0.f;
#pragma unroll
      for (int c = 0; c < 13; ++c) {
        if (c < cmax) {
          float p = __expf(tv[c] - mx);
          tv[c] = p;
          sum += p;
        }
      }
#pragma unroll
      for (int off = 1; off < 16; off <<= 1) sum += __shfl_xor(sum, off);
      float inv = 1.f / sum;
#pragma unroll
      for (int c = 0; c < 13; ++c) {
        if (c < cmax)
          Ps[(w * 16 + quad * 4 + r) * 232 + c * 16 + l] = f2bf(tv[c] * inv);
      }
    }
    // O = P @ V
    int smax = t0 + w * 16 + 16;
    if (smax > T_SEQ) smax = T_SEQ;
    const int ksteps = (smax + 31) >> 5;
    f32x4_t oa[4];
#pragma unroll
    for (int d = 0; d < 4; ++d) oa[d] = (f32x4_t){0.f, 0.f, 0.f, 0.f};
    for (int ks = 0; ks < ksteps; ++ks) {
      bf16x8_t pa = *(const bf16x8_t*)&Ps[(w * 16 + l) * 232 + ks * 32 + quad * 8];
#pragma unroll
      for (int d = 0; d < 4; ++d) {
        bf16x8_t vb = *(const bf16x8_t*)&Vt[(d * 16 + l) * 232 + ks * 32 + quad * 8];
        oa[d] = __builtin_amdgcn_mfma_f32_16x16x32_bf16(pa, vb, oa[d], 0, 0, 0);
      }
    }
#pragma unroll
    for (int d = 0; d < 4; ++d) {
#pragma unroll
      for (int r = 0; r < 4; ++r) {
        int t = t0 + w * 16 + quad * 4 + r;
        if (t < T_SEQ)
          att[((size_t)b * T_SEQ + t) * EMBD + h * 64 + d * 16 + l] = f2bf(oa[d][r]);
      }
    }
  }
}

extern "C" void kernel_launch(void* const* d_in, const int* in_sizes, int n_in,
                              void* d_out, int out_size, void* d_ws, size_t ws_size,
                              hipStream_t stream) {
  const void* x     = d_in[0];
  const void* Wq    = d_in[1];
  const void* Wk    = d_in[2];
  const void* Wv    = d_in[3];
  const void* Wproj = d_in[4];
  const void* bproj = d_in[5];
  const void* W1    = d_in[6];
  const void* b1    = d_in[7];
  const void* W2    = d_in[8];
  const void* b2    = d_in[9];
  const void* g1    = d_in[10];
  const void* be1   = d_in[11];
  const void* g2    = d_in[12];
  const void* be2   = d_in[13];

  char* ws = (char*)d_ws;
  unsigned short* wqkv_t  = (unsigned short*)(ws + OFF_WQKV);
  unsigned short* wproj_t = (unsigned short*)(ws + OFF_WPROJ);
  unsigned short* w1_t    = (unsigned short*)(ws + OFF_W1);
  unsigned short* w2_t    = (unsigned short*)(ws + OFF_W2);
  float*          bias_f  = (float*)(ws + OFF_BIAS);
  int*            flag    = (int*)(ws + OFF_FLAG);

  // Adaptive batch-chunking: footprint = OFF_DYN + Bc*200*6144 bytes.
  int Bc = BATCH;
  while (Bc > 1 && OFF_DYN + (size_t)Bc * T_SEQ * 6144 > ws_size) Bc >>= 1;
  if (OFF_DYN + (size_t)Bc * T_SEQ * 6144 > ws_size) return;
  const int NC = BATCH / Bc;
  const int Mc = Bc * T_SEQ;
  const int NY = (Mc + 127) / 128;
  const int NYpad = (NY + 7) & ~7;

  char* bufA = ws + OFF_DYN;                  // qkv; then x2(bf16)+h2
  char* bufB = bufA + (size_t)Mc * 2304;      // h; then att
  char* bufC = bufB + (size_t)Mc * 768;       // mid
  unsigned short* qkv = (unsigned short*)bufA;
  unsigned short* x2  = (unsigned short*)bufA;
  unsigned short* h2  = (unsigned short*)(bufA + (size_t)Mc * 768);
  unsigned short* hb  = (unsigned short*)bufB;
  unsigned short* mid = (unsigned short*)bufC;

  detect_dtype<<<1, 256, 0, stream>>>((const unsigned short*)x, flag);
  cvt_all<<<15, 256, 0, stream>>>(bproj, b1, b2, g1, be1, g2, be2, bias_f, flag);
  pack_all<<<6912, 256, 0, stream>>>(Wq, Wk, Wv, Wproj, W1, W2, ws, flag);

  for (int c = 0; c < NC; ++c) {
    const int row0 = c * Bc * T_SEQ;
    // 1. h = LN1(x[chunk])
    ln_kernel<<<Mc / 4, 256, 0, stream>>>(x, row0, bias_f + 2304, bias_f + 2688, hb, -1, flag);
    // 2. qkv = h @ [Wq|Wk|Wv]
    gemm_kernel<0><<<9 * NYpad, 256, 0, stream>>>(
        hb, 384, wqkv_t, 384, nullptr, nullptr, 0, 0, qkv, 1152, 0, Mc, 9, NY, nullptr);
    // 3. att = softmax(causal(q k^T * 384^-0.5)) v  (att overlays h)
    attn_kernel<<<Bc * NHEAD, 256, 0, stream>>>(qkv, hb);
    // 4. x2 = x[chunk] + att @ Wproj + bproj  (bf16, overlays dead qkv)
    gemm_kernel<2><<<3 * NYpad, 256, 0, stream>>>(
        hb, 384, wproj_t, 384, bias_f + 0, x, 384, row0, x2, 384, 0, Mc, 3, NY, flag);
    // 5. h2 = LN2(x2)
    ln_kernel<<<Mc / 4, 256, 0, stream>>>(x2, 0, bias_f + 3072, bias_f + 3456, h2, 1, nullptr);
    // 6. mid = relu(h2 @ W1 + b1)
    gemm_kernel<1><<<12 * NYpad, 256, 0, stream>>>(
        h2, 384, w1_t, 384, bias_f + 384, nullptr, 0, 0, mid, 1536, 0, Mc, 12, NY, nullptr);
    // 7. out[chunk] = x2 + mid @ W2 + b2
    gemm_kernel<3><<<3 * NYpad, 256, 0, stream>>>(
        mid, 1536, w2_t, 1536, bias_f + 1920, x2, 384, 0, d_out, 384, row0, Mc, 3, NY, flag);
  }
}